// Round 6
// baseline (117.108 us; speedup 1.0000x reference)
//
#include <hip/hip_runtime.h>
#include <stdint.h>

typedef float v4f __attribute__((ext_vector_type(4)));
typedef int   v8i __attribute__((ext_vector_type(8)));

#define PEX_STRIDE 1156
#define CSTRIDE 570   // u64 per shifted copy (63 rows x 9 slots); 2*570 mod 32 = 20
#define WS_IMG8   0
#define WS_BFRAG  1048576
#define WS_PEX    1064960
#define WS_RESULT 9994240
#define WS_CAND   14188544

__device__ inline unsigned char f32_to_e4m3(float v) {
    if (!(v > 0.0f)) return 0;
    if (v >= 448.0f) return 0x7e;
    if (v < 0.015625f) {                       // subnormal: m * 2^-9
        int m = (int)(v * 512.0f + 0.5f);
        if (m > 7) return 0x08;
        return (unsigned char)m;
    }
    unsigned int u = __float_as_uint(v) + 0x00080000u;  // round into bit 20
    int e = (int)((u >> 23) & 0xff) - 127;
    int m3 = (int)(u >> 20) & 7;
    int e8 = e + 7;
    if (e8 >= 16) return 0x7e;
    return (unsigned char)((e8 << 3) | m3);
}

// Fused front kernel.
// blocks [0,1024): wrapped row prefix sums + fp8 image emit (row L1-hot)
// blocks [1024,2080): zero d_out
// blocks [2080,2144): A-fragment psf table for the K=128 MX MFMA:
//   abuf[kb4][lane][b] fp8 = psf[z][a][b]*cos(2pi(a+b-32)/1024)*1024,
//   z=lane&15, a=4*kb4+(lane>>4), b=0..31; also zeroes cnt[0] (candidates)
//   and cnt[1] (block-done counter for the fused maxpool+final kernel).
__global__ void k_pex(const float* __restrict__ img, float* __restrict__ pex,
                      uint32_t* __restrict__ img8, const float* __restrict__ psf,
                      unsigned char* __restrict__ bf, unsigned int* cnt,
                      float4* __restrict__ out, int n4) {
    __shared__ float wtot[4];
    int blk = blockIdx.x, t = threadIdx.x;
    if (blk >= 1024) {
        if (blk < 2080) {
            int i = (blk - 1024) * 256 + t;
            if (i < n4) { float4 z; z.x = z.y = z.z = z.w = 0.f; out[i] = z; }
        } else {
            int u = (blk - 2080) * 256 + t;   // 16384 = 8 kb4 x 64 lanes x 32 B
            if (u == 0) { cnt[0] = 0u; cnt[1] = 0u; }
            int kb4 = u >> 11; int l = (u >> 5) & 63; int b = u & 31;
            int z = l & 15; int a = kb4 * 4 + (l >> 4);
            float p = psf[z * 1024 + a * 32 + b];
            float c = cosf((float)(a + b - 32) * (6.283185307179586f / 1024.0f));
            bf[u] = f32_to_e4m3(p * c * 1024.0f);
        }
        return;
    }
    int r = blk;
    const float* row = img + r * 1024;
    float s[5];
    float acc = 0.f;
    int base = t * 5;
    #pragma unroll
    for (int j = 0; j < 5; j++) {
        int c = base + j;
        float v = (c < 1152) ? row[(c - 64) & 1023] : 0.f;
        acc += v; s[j] = acc;
    }
    float sc = acc;
    int lane = t & 63, w = t >> 6;
    #pragma unroll
    for (int off = 1; off < 64; off <<= 1) {
        float v = __shfl_up(sc, off, 64);
        if (lane >= off) sc += v;
    }
    if (lane == 63) wtot[w] = sc;
    __syncthreads();
    float wbase = 0.f;
    #pragma unroll
    for (int i = 0; i < 3; i++) if (i < w) wbase += wtot[i];
    float excl = wbase + (sc - acc);
    float* prow = pex + r * PEX_STRIDE;
    if (t == 0) prow[0] = 0.f;
    #pragma unroll
    for (int j = 0; j < 5; j++) {
        int c = base + j;
        if (c < 1152) prow[c + 1] = excl + s[j];
    }
    float4 v4 = *(const float4*)(row + 4 * t);
    img8[r * 256 + t] = (uint32_t)f32_to_e4m3(v4.x)
                      | ((uint32_t)f32_to_e4m3(v4.y) << 8)
                      | ((uint32_t)f32_to_e4m3(v4.z) << 16)
                      | ((uint32_t)f32_to_e4m3(v4.w) << 24);
}

// 32-byte LDS fragment load (8B-aligned) -> v8i for the MX MFMA B operand.
// Built via constant-index element inserts: guaranteed register-only.
__device__ inline v8i ldsB(const unsigned long long* p) {
    unsigned long long q0 = p[0], q1 = p[1], q2 = p[2], q3 = p[3];
    v8i v;
    v[0] = (int)(unsigned int)q0;  v[1] = (int)(unsigned int)(q0 >> 32);
    v[2] = (int)(unsigned int)q1;  v[3] = (int)(unsigned int)(q1 >> 32);
    v[4] = (int)(unsigned int)q2;  v[5] = (int)(unsigned int)(q2 >> 32);
    v[6] = (int)(unsigned int)q3;  v[7] = (int)(unsigned int)(q3 >> 32);
    return v;
}

// MFMA conv (MX-scaled fp8, K=128 = 4 psf rows) with FUSED background.
// Tile 32 rows x 32 cols, 1024 blocks x 256 thr (4 waves): 4 blocks/CU
// (LDS 36.5 KB) so staging/bg latency of one block hides under another's
// MFMA phase. Wave: (w>>1)=row group of 16, (w&1)=col half. Per-chain:
// 2 interleaved accumulators, 16 MFMAs, B rows from 8 shifted LDS copies.
__global__ __launch_bounds__(256, 4) void k_conv(
    const unsigned long long* __restrict__ img64,
    const unsigned char* __restrict__ bfrag,
    const float* __restrict__ pex, float* __restrict__ result) {
    __shared__ unsigned long long sm[8 * CSTRIDE];   // 36480 B
    __shared__ float rbp[4][5][4];                   // [si][k][chunk] partials
    __shared__ float rbv[4][5];                      // transformed bg multipliers
    int tid = threadIdx.x;
    int wave = tid >> 6, lane = tid & 63;
    int b = blockIdx.x;
    int tr = b >> 5, tc = b & 31;
    int r0 = tr * 32, c0 = tc * 32;

    for (int u = tid; u < 441; u += 256) {    // 63 rows x 7 slots
        int dr = u / 7;
        int x8 = u - dr * 7;
        int row = (r0 + dr - 16) & 1023;
        int cb0 = (c0 + x8 * 8 - 16) & 1023;
        int cb1 = (cb0 + 8) & 1023;
        unsigned long long lo = img64[row * 128 + (cb0 >> 3)];
        unsigned long long hi = img64[row * 128 + (cb1 >> 3)];
        int dst = dr * 9 + x8;
        sm[dst] = lo;
        #pragma unroll
        for (int s = 1; s < 8; s++)
            sm[s * CSTRIDE + dst] = (lo >> (8 * s)) | (hi << (64 - 8 * s));
    }

    // fused bg partial sums: 4 sampled rows x 5 sampled cols = 20 lanes,
    // dy-chunk of 32 per wave (4 waves cover dy=-63..63)
    if (lane < 20) {
        int si = lane / 5, kc = lane - si * 5;
        int baserow = r0 + si * 8 + 3;
        int n = c0 + 8 * kc;                  // sampled column (c0+32 wraps ok)
        int j0 = wave * 32;
        int j1 = j0 + 32; if (j1 > 127) j1 = 127;
        float acc = 0.f;
        for (int j = j0; j < j1; j++) {
            int dy = j - 63;
            int ady = dy < 0 ? -dy : dy;
            int w = (int)sqrtf((float)(4095 - ady * ady));
            const float* p = pex + ((baserow + dy) & 1023) * PEX_STRIDE + n;
            acc += p[65 + w] - p[64 - w];
        }
        rbp[si][kc][wave] = acc;
    }
    __syncthreads();
    if (tid < 20) {
        int si = tid / 5, kc = tid - si * 5;
        float s = 0.f;
        #pragma unroll
        for (int h = 0; h < 4; h++) s += rbp[si][kc][h];
        const float kk = (float)(1.0 / (3.14159265358979323846 * 4096.0));
        rbv[si][kc] = 1.0f / ((s * kk + 1.0f) * 1024.0f);  // /1024 undoes psf scale
    }

    int i0 = (wave >> 1) * 16;                // tile row group
    int cw = (wave & 1) * 16;                 // col half
    int q = lane >> 4;                        // K-block row offset (and C row grp)
    int n = lane & 15;
    // B-fragment base: bytes (cw+n)..(cw+n+31) of patch row (i0+q+...),
    // from shifted copy (n&7), 4 consecutive u64 slots.
    const unsigned long long* bpq =
        sm + (n & 7) * CSTRIDE + ((cw + n) >> 3) + (i0 + q) * 9;
    const v8i* bfA = (const v8i*)(bfrag + lane * 32);   // A rows for this lane

    float zmax[16];
    #pragma unroll
    for (int h = 0; h < 2; h++) {
        #pragma unroll
        for (int p = 0; p < 4; p++) {
            const unsigned long long* tp = bpq + (h * 8 + p) * 9;
            v4f a0 = (v4f)0.0f, a1 = (v4f)0.0f;
            v8i bcur = ldsB(tp);
            #pragma unroll
            for (int kb4 = 0; kb4 < 8; kb4++) {
                v8i bnxt = ldsB(tp + (4 * (kb4 + 1)) * 9);
                v8i av = bfA[kb4 << 6];       // bfrag + kb4*2048 + lane*32
                a0 = __builtin_amdgcn_mfma_scale_f32_16x16x128_f8f6f4(
                        av, bcur, a0, 0, 0, 0, 0x7f7f7f7f, 0, 0x7f7f7f7f);
                a1 = __builtin_amdgcn_mfma_scale_f32_16x16x128_f8f6f4(
                        av, bnxt, a1, 0, 0, 0, 0x7f7f7f7f, 0, 0x7f7f7f7f);
                bcur = bnxt;
            }
            // z-max in registers, wave-wide (C row = 4q+reg = z)
            float m0 = fmaxf(fmaxf(a0.x, a0.y), fmaxf(a0.z, a0.w));
            m0 = fmaxf(m0, __shfl_xor(m0, 16, 64));
            m0 = fmaxf(m0, __shfl_xor(m0, 32, 64));
            zmax[h * 8 + p] = m0;
            float m1 = fmaxf(fmaxf(a1.x, a1.y), fmaxf(a1.z, a1.w));
            m1 = fmaxf(m1, __shfl_xor(m1, 16, 64));
            m1 = fmaxf(m1, __shfl_xor(m1, 32, 64));
            zmax[h * 8 + p + 4] = m1;
            __builtin_amdgcn_sched_barrier(0);   // bound liveness to one chain
        }
    }
    __syncthreads();   // rbv written pre-MFMA by threads<20; make visible to all

    int uu = cw + n;                          // 0..31 within tile
    int kc = uu >> 3;
    float fr = (float)(uu & 7) * 0.125f;
    int gcol = c0 + uu;
    #pragma unroll
    for (int c4 = 0; c4 < 4; c4++) {
        float m01 = (q & 1) ? zmax[c4 * 4 + 1] : zmax[c4 * 4 + 0];
        float m23 = (q & 1) ? zmax[c4 * 4 + 3] : zmax[c4 * 4 + 2];
        float m = (q & 2) ? m23 : m01;
        int lrow = i0 + c4 * 4 + q;           // 0..31
        int sil = lrow >> 3;
        float rv0 = rbv[sil][kc], rv1 = rbv[sil][kc + 1];
        float rbl = rv0 + fr * (rv1 - rv0);
        result[(r0 + lrow) * 1024 + gcol] = m * rbl;
    }
}

// fused 32x32 stride-1 maxpool + candidate extraction + (last block) sort/emit.
// Every block increments a device-scope done counter after threadfence; the
// 256th block runs the former k_final phase — saves one launch+teardown.
// hr (pool phase) and keys (sort phase) are never live simultaneously ->
// union keeps LDS at 60.8 KB (same footprint as the always-passing k_maxcand).
__global__ __launch_bounds__(256) void k_maxfin(
    const float* __restrict__ result, const float* __restrict__ image,
    unsigned int* cnt, unsigned long long* cand, float* __restrict__ out) {
    __shared__ float ls[95 * 96];
    __shared__ union {
        float hr[95 * 64];
        unsigned long long keys[2048];
    } ov;
    __shared__ float wmax[4];
    __shared__ unsigned int lastflag;
    int bx = blockIdx.x & 15, by = blockIdx.x >> 4;
    int i0 = by * 64, j0 = bx * 64;
    int t = threadIdx.x;
    // fast reject: tile max over the 64x64 core (float4 loads)
    const float4* cb4 = (const float4*)(result + i0 * 1024 + j0);
    float mx = -3.4e38f;
    #pragma unroll
    for (int k = 0; k < 4; k++) {
        int idx = k * 256 + t;                 // 1024 float4: row idx>>4, col4 idx&15
        float4 v = cb4[(idx >> 4) * 256 + (idx & 15)];
        mx = fmaxf(mx, fmaxf(fmaxf(v.x, v.y), fmaxf(v.z, v.w)));
    }
    #pragma unroll
    for (int m = 1; m < 64; m <<= 1) mx = fmaxf(mx, __shfl_xor(mx, m, 64));
    if ((t & 63) == 0) wmax[t >> 6] = mx;
    __syncthreads();
    float tmax = fmaxf(fmaxf(wmax[0], wmax[1]), fmaxf(wmax[2], wmax[3]));
    if (tmax > 2.0f) {
        // slow path: full separable pooling on the 95x95 halo
        for (int idx = t; idx < 95 * 95; idx += 256) {
            int r = idx / 95, c = idx - r * 95;
            int gr = i0 - 16 + r, gc = j0 - 16 + c;
            float v = -3.4e38f;
            if ((unsigned)gr < 1024u && (unsigned)gc < 1024u) v = result[gr * 1024 + gc];
            ls[r * 96 + c] = v;
        }
        __syncthreads();
        for (int idx = t; idx < 95 * 64; idx += 256) {
            int r = idx >> 6, c = idx & 63;
            const float* p = ls + r * 96 + c;
            float m = p[0];
            #pragma unroll
            for (int d = 1; d < 32; d++) m = fmaxf(m, p[d]);
            ov.hr[idx] = m;
        }
        __syncthreads();
        for (int idx = t; idx < 64 * 64; idx += 256) {
            int r = idx >> 6, c = idx & 63;
            const float* p = ov.hr + r * 64 + c;
            float m = p[0];
            #pragma unroll
            for (int d = 1; d < 32; d++) m = fmaxf(m, p[d * 64]);
            float v = ls[(r + 16) * 96 + (c + 16)];
            int gi = i0 + r, gj = j0 + c;
            if (gi >= 1 && gj >= 1 && v > 2.0f && v == m) {
                unsigned int k = atomicAdd(cnt, 1u);
                if (k < 2048)
                    cand[k] = ((unsigned long long)__float_as_uint(v) << 32)
                            | (unsigned int)(~(unsigned int)(gi * 1024 + gj));
            }
        }
    }
    // completion protocol: device-scope release, then count; last block proceeds
    __threadfence();
    __syncthreads();
    if (t == 0) lastflag = (atomicAdd(&cnt[1], 1u) == 255u) ? 1u : 0u;
    __syncthreads();
    if (lastflag == 0u) return;
    __threadfence();                            // acquire side

    int n = (int)cnt[0]; if (n > 2048) n = 2048;
    if (n == 0) return;                         // d_out already zeroed by k_pex
    __syncthreads();                            // hr dead; reuse as keys
    for (int k = t; k < 2048; k += 256) ov.keys[k] = (k < n) ? cand[k] : 0ull;
    __syncthreads();
    for (int size = 2; size <= 2048; size <<= 1) {
        for (int stride = size >> 1; stride > 0; stride >>= 1) {
            for (int i = t; i < 2048; i += 256) {
                int ixj = i ^ stride;
                if (ixj > i) {
                    unsigned long long a = ov.keys[i], b = ov.keys[ixj];
                    bool sw = ((i & size) == 0) ? (a < b) : (a > b);  // descending
                    if (sw) { ov.keys[i] = b; ov.keys[ixj] = a; }
                }
            }
            __syncthreads();
        }
    }
    float* roipos = out;
    float* intensity = out + 2048;
    float* rois = out + 3072;
    float* validf = out + 3072 + 1048576;
    int nw = n < 1024 ? n : 1024;
    for (int tt = t; tt < nw; tt += 256) {
        unsigned long long key = ov.keys[tt];
        float val = __uint_as_float((unsigned int)(key >> 32));
        unsigned int p = ~(unsigned int)key;
        int y = (int)(p >> 10), x = (int)(p & 1023);
        int roy = y - 16, rox = x - 16;
        bool valid = (roy >= 0 && roy < 992 && rox >= 0 && rox < 992);
        int royc = roy < 0 ? 0 : (roy > 992 ? 992 : roy);
        int roxc = rox < 0 ? 0 : (rox > 992 ? 992 : rox);
        roipos[2 * tt]     = valid ? (float)royc : 0.f;
        roipos[2 * tt + 1] = valid ? (float)roxc : 0.f;
        intensity[tt]      = valid ? val : 0.f;
        validf[tt]         = valid ? 1.f : 0.f;
    }
    __syncthreads();
    for (int k = 0; k < nw; k++) {
        unsigned long long key = ov.keys[k];
        unsigned int p = ~(unsigned int)key;
        int y = (int)(p >> 10), x = (int)(p & 1023);
        int roy = y - 16, rox = x - 16;
        if (!(roy >= 0 && roy < 992 && rox >= 0 && rox < 992)) continue;
        #pragma unroll
        for (int m = 0; m < 4; m++) {
            int idx = t + 256 * m;
            int u = idx >> 5, vv = idx & 31;
            rois[k * 1024 + idx] = image[(roy + u) * 1024 + (rox + vv)];
        }
    }
}

extern "C" void kernel_launch(void* const* d_in, const int* in_sizes, int n_in,
                              void* d_out, int out_size, void* d_ws, size_t ws_size,
                              hipStream_t stream) {
    const float* image = (const float*)d_in[0];
    const float* psf   = (const float*)d_in[1];
    float* out = (float*)d_out;
    char* ws = (char*)d_ws;
    unsigned char* img8  = (unsigned char*)(ws + WS_IMG8);
    unsigned char* bfrag = (unsigned char*)(ws + WS_BFRAG);
    float* pex = (float*)(ws + WS_PEX);
    float* result = (float*)(ws + WS_RESULT);
    unsigned int* cnt = (unsigned int*)(ws + WS_CAND);
    unsigned long long* cand = (unsigned long long*)(ws + WS_CAND + 16);

    int n4 = out_size / 4;
    hipLaunchKernelGGL(k_pex,    dim3(2144), dim3(256), 0, stream,
                       image, pex, (uint32_t*)img8, psf, bfrag, cnt, (float4*)d_out, n4);
    hipLaunchKernelGGL(k_conv,   dim3(1024), dim3(256), 0, stream,
                       (const unsigned long long*)img8, bfrag, pex, result);
    hipLaunchKernelGGL(k_maxfin, dim3(256),  dim3(256), 0, stream,
                       result, image, cnt, cand, out);
}

// Round 7
// 95.920 us; speedup vs baseline: 1.2209x; 1.2209x over previous
//
#include <hip/hip_runtime.h>
#include <stdint.h>

typedef float v4f __attribute__((ext_vector_type(4)));
typedef int   v8i __attribute__((ext_vector_type(8)));

#define PEX_STRIDE 1156
#define CSTRIDE 858   // u64 per shifted copy; 2*858 mod 32 = 20 -> uniform 4/bank b64 reads
#define WS_IMG8   0
#define WS_BFRAG  1048576
#define WS_PEX    1064960
#define WS_RESULT 9994240
#define WS_CAND   14188544

__device__ inline unsigned char f32_to_e4m3(float v) {
    if (!(v > 0.0f)) return 0;
    if (v >= 448.0f) return 0x7e;
    if (v < 0.015625f) {                       // subnormal: m * 2^-9
        int m = (int)(v * 512.0f + 0.5f);
        if (m > 7) return 0x08;
        return (unsigned char)m;
    }
    unsigned int u = __float_as_uint(v) + 0x00080000u;  // round into bit 20
    int e = (int)((u >> 23) & 0xff) - 127;
    int m3 = (int)(u >> 20) & 7;
    int e8 = e + 7;
    if (e8 >= 16) return 0x7e;
    return (unsigned char)((e8 << 3) | m3);
}

// Fused front kernel.
// blocks [0,1024): wrapped row prefix sums + fp8 image emit (row L1-hot)
// blocks [1024,2080): zero d_out
// blocks [2080,2144): A-fragment psf table for the K=128 MX MFMA:
//   abuf[kb4][lane][b] fp8 = psf[z][a][b]*cos(2pi(a+b-32)/1024)*1024,
//   z=lane&15, a=4*kb4+(lane>>4), b=0..31; also zeroes cnt[0].
__global__ void k_pex(const float* __restrict__ img, float* __restrict__ pex,
                      uint32_t* __restrict__ img8, const float* __restrict__ psf,
                      unsigned char* __restrict__ bf, unsigned int* cnt,
                      float4* __restrict__ out, int n4) {
    __shared__ float wtot[4];
    int blk = blockIdx.x, t = threadIdx.x;
    if (blk >= 1024) {
        if (blk < 2080) {
            int i = (blk - 1024) * 256 + t;
            if (i < n4) { float4 z; z.x = z.y = z.z = z.w = 0.f; out[i] = z; }
        } else {
            int u = (blk - 2080) * 256 + t;   // 16384 = 8 kb4 x 64 lanes x 32 B
            if (u == 0) cnt[0] = 0u;
            int kb4 = u >> 11; int l = (u >> 5) & 63; int b = u & 31;
            int z = l & 15; int a = kb4 * 4 + (l >> 4);
            float p = psf[z * 1024 + a * 32 + b];
            float c = cosf((float)(a + b - 32) * (6.283185307179586f / 1024.0f));
            bf[u] = f32_to_e4m3(p * c * 1024.0f);
        }
        return;
    }
    int r = blk;
    const float* row = img + r * 1024;
    float s[5];
    float acc = 0.f;
    int base = t * 5;
    #pragma unroll
    for (int j = 0; j < 5; j++) {
        int c = base + j;
        float v = (c < 1152) ? row[(c - 64) & 1023] : 0.f;
        acc += v; s[j] = acc;
    }
    float sc = acc;
    int lane = t & 63, w = t >> 6;
    #pragma unroll
    for (int off = 1; off < 64; off <<= 1) {
        float v = __shfl_up(sc, off, 64);
        if (lane >= off) sc += v;
    }
    if (lane == 63) wtot[w] = sc;
    __syncthreads();
    float wbase = 0.f;
    #pragma unroll
    for (int i = 0; i < 3; i++) if (i < w) wbase += wtot[i];
    float excl = wbase + (sc - acc);
    float* prow = pex + r * PEX_STRIDE;
    if (t == 0) prow[0] = 0.f;
    #pragma unroll
    for (int j = 0; j < 5; j++) {
        int c = base + j;
        if (c < 1152) prow[c + 1] = excl + s[j];
    }
    float4 v4 = *(const float4*)(row + 4 * t);
    img8[r * 256 + t] = (uint32_t)f32_to_e4m3(v4.x)
                      | ((uint32_t)f32_to_e4m3(v4.y) << 8)
                      | ((uint32_t)f32_to_e4m3(v4.z) << 16)
                      | ((uint32_t)f32_to_e4m3(v4.w) << 24);
}

// 32-byte LDS fragment load (8B-aligned) -> v8i for the MX MFMA B operand.
// Built via constant-index element inserts: guaranteed register-only.
__device__ inline v8i ldsB(const unsigned long long* p) {
    unsigned long long q0 = p[0], q1 = p[1], q2 = p[2], q3 = p[3];
    v8i v;
    v[0] = (int)(unsigned int)q0;  v[1] = (int)(unsigned int)(q0 >> 32);
    v[2] = (int)(unsigned int)q1;  v[3] = (int)(unsigned int)(q1 >> 32);
    v[4] = (int)(unsigned int)q2;  v[5] = (int)(unsigned int)(q2 >> 32);
    v[6] = (int)(unsigned int)q3;  v[7] = (int)(unsigned int)(q3 >> 32);
    return v;
}

// MFMA conv (MX-scaled fp8, K=128 = 4 psf rows) with FUSED background.
// Round-4 structure (64x32 tile, 512 thr, 2 blocks/CU) — the best-measured.
// Prologue latency fixes: bg's scattered pex loads are issued BEFORE the
// staging loop (longest-latency ops first, overlap with staging), and the
// bg dy-loop is fully unrolled (16 iters, last predicated) so all loads
// issue independently instead of a runtime-bound serial loop.
__global__ __launch_bounds__(512, 4) void k_conv(
    const unsigned long long* __restrict__ img64,
    const unsigned char* __restrict__ bfrag,
    const float* __restrict__ pex, float* __restrict__ result) {
    __shared__ unsigned long long sm[8 * CSTRIDE];   // 54912 B
    __shared__ float rbp[8][5][8];                   // [si][k][chunk] partials
    __shared__ float rbv[8][5];                      // transformed bg multipliers
    int tid = threadIdx.x;
    int wave = tid >> 6, lane = tid & 63;
    int b = blockIdx.x;
    int tr = b >> 5, tc = b & 31;
    int r0 = tr * 64, c0 = tc * 32;

    // fused bg partial sums first: value v = lane (si=v/5, k=v%5), dy-chunk =
    // wave. Fully unrolled; j==127 (dy=64) predicated off for wave 7.
    if (lane < 40) {
        int si = lane / 5, kc = lane - si * 5;
        int baserow = r0 + si * 8 + 3;
        int n = c0 + 8 * kc;                  // sampled column (c0+32 wraps ok)
        int j0 = wave * 16;
        float acc = 0.f;
        #pragma unroll
        for (int u = 0; u < 16; u++) {
            int j = j0 + u;
            if (j < 127) {
                int dy = j - 63;
                int ady = dy < 0 ? -dy : dy;
                int w = (int)sqrtf((float)(4095 - ady * ady));
                const float* p = pex + ((baserow + dy) & 1023) * PEX_STRIDE + n;
                acc += p[65 + w] - p[64 - w];
            }
        }
        rbp[si][kc][wave] = acc;
    }

    for (int u = tid; u < 665; u += 512) {    // 95 rows x 7 slots
        int dr = u / 7;
        int x8 = u - dr * 7;
        int row = (r0 + dr - 16) & 1023;
        int cb0 = (c0 + x8 * 8 - 16) & 1023;
        int cb1 = (cb0 + 8) & 1023;
        unsigned long long lo = img64[row * 128 + (cb0 >> 3)];
        unsigned long long hi = img64[row * 128 + (cb1 >> 3)];
        int dst = dr * 9 + x8;
        sm[dst] = lo;
        #pragma unroll
        for (int s = 1; s < 8; s++)
            sm[s * CSTRIDE + dst] = (lo >> (8 * s)) | (hi << (64 - 8 * s));
    }
    __syncthreads();
    if (tid < 40) {
        int si = tid / 5, kc = tid - si * 5;
        float s = 0.f;
        #pragma unroll
        for (int h = 0; h < 8; h++) s += rbp[si][kc][h];
        const float kk = (float)(1.0 / (3.14159265358979323846 * 4096.0));
        rbv[si][kc] = 1.0f / ((s * kk + 1.0f) * 1024.0f);  // /1024 undoes psf scale
    }

    int i0 = (wave >> 1) * 16;                // tile row group
    int cw = (wave & 1) * 16;                 // col half
    int q = lane >> 4;                        // K-block row offset (and C row grp)
    int n = lane & 15;
    // B-fragment base: bytes (cw+n)..(cw+n+31) of patch row (i0+q+cc+4*kb4),
    // from shifted copy (n&7), 4 consecutive u64 slots.
    const unsigned long long* bpq =
        sm + (n & 7) * CSTRIDE + ((cw + n) >> 3) + (i0 + q) * 9;
    const v8i* bfA = (const v8i*)(bfrag + lane * 32);   // A rows for this lane

    float zmax[16];
    #pragma unroll
    for (int h = 0; h < 2; h++) {
        #pragma unroll
        for (int p = 0; p < 4; p++) {
            const unsigned long long* tp = bpq + (h * 8 + p) * 9;
            v4f a0 = (v4f)0.0f, a1 = (v4f)0.0f;
            v8i bcur = ldsB(tp);
            #pragma unroll
            for (int kb4 = 0; kb4 < 8; kb4++) {
                v8i bnxt = ldsB(tp + (4 * (kb4 + 1)) * 9);
                v8i av = bfA[kb4 << 6];       // bfrag + kb4*2048 + lane*32
                a0 = __builtin_amdgcn_mfma_scale_f32_16x16x128_f8f6f4(
                        av, bcur, a0, 0, 0, 0, 0x7f7f7f7f, 0, 0x7f7f7f7f);
                a1 = __builtin_amdgcn_mfma_scale_f32_16x16x128_f8f6f4(
                        av, bnxt, a1, 0, 0, 0, 0x7f7f7f7f, 0, 0x7f7f7f7f);
                bcur = bnxt;
            }
            // z-max in registers, wave-wide (C row = 4q+reg = z)
            float m0 = fmaxf(fmaxf(a0.x, a0.y), fmaxf(a0.z, a0.w));
            m0 = fmaxf(m0, __shfl_xor(m0, 16, 64));
            m0 = fmaxf(m0, __shfl_xor(m0, 32, 64));
            zmax[h * 8 + p] = m0;
            float m1 = fmaxf(fmaxf(a1.x, a1.y), fmaxf(a1.z, a1.w));
            m1 = fmaxf(m1, __shfl_xor(m1, 16, 64));
            m1 = fmaxf(m1, __shfl_xor(m1, 32, 64));
            zmax[h * 8 + p + 4] = m1;
            __builtin_amdgcn_sched_barrier(0);   // bound liveness to one chain
        }
    }
    __syncthreads();   // rbv written pre-MFMA by threads<40; make visible to all

    int uu = cw + n;                          // 0..31 within tile
    int kc = uu >> 3;
    float fr = (float)(uu & 7) * 0.125f;
    int gcol = c0 + uu;
    #pragma unroll
    for (int c4 = 0; c4 < 4; c4++) {
        float m01 = (q & 1) ? zmax[c4 * 4 + 1] : zmax[c4 * 4 + 0];
        float m23 = (q & 1) ? zmax[c4 * 4 + 3] : zmax[c4 * 4 + 2];
        float m = (q & 2) ? m23 : m01;
        int lrow = i0 + c4 * 4 + q;           // 0..63
        int sil = lrow >> 3;
        float rv0 = rbv[sil][kc], rv1 = rbv[sil][kc + 1];
        float rbl = rv0 + fr * (rv1 - rv0);
        result[(r0 + lrow) * 1024 + gcol] = m * rbl;
    }
}

// fused 32x32 stride-1 maxpool + candidate extraction, with fast reject.
__global__ __launch_bounds__(256) void k_maxcand(const float* __restrict__ result,
                                                 unsigned int* cnt,
                                                 unsigned long long* cand) {
    __shared__ float ls[95 * 96];
    __shared__ float hr[95 * 64];
    __shared__ float wmax[4];
    int bx = blockIdx.x & 15, by = blockIdx.x >> 4;
    int i0 = by * 64, j0 = bx * 64;
    int t = threadIdx.x;
    // fast reject: tile max over the 64x64 core (float4 loads)
    const float4* cb4 = (const float4*)(result + i0 * 1024 + j0);
    float mx = -3.4e38f;
    #pragma unroll
    for (int k = 0; k < 4; k++) {
        int idx = k * 256 + t;                 // 1024 float4: row idx>>4, col4 idx&15
        float4 v = cb4[(idx >> 4) * 256 + (idx & 15)];
        mx = fmaxf(mx, fmaxf(fmaxf(v.x, v.y), fmaxf(v.z, v.w)));
    }
    #pragma unroll
    for (int m = 1; m < 64; m <<= 1) mx = fmaxf(mx, __shfl_xor(mx, m, 64));
    if ((t & 63) == 0) wmax[t >> 6] = mx;
    __syncthreads();
    float tmax = fmaxf(fmaxf(wmax[0], wmax[1]), fmaxf(wmax[2], wmax[3]));
    if (tmax <= 2.0f) return;

    // slow path: full separable pooling on the 95x95 halo
    for (int idx = t; idx < 95 * 95; idx += 256) {
        int r = idx / 95, c = idx - r * 95;
        int gr = i0 - 16 + r, gc = j0 - 16 + c;
        float v = -3.4e38f;
        if ((unsigned)gr < 1024u && (unsigned)gc < 1024u) v = result[gr * 1024 + gc];
        ls[r * 96 + c] = v;
    }
    __syncthreads();
    for (int idx = t; idx < 95 * 64; idx += 256) {
        int r = idx >> 6, c = idx & 63;
        const float* p = ls + r * 96 + c;
        float m = p[0];
        #pragma unroll
        for (int d = 1; d < 32; d++) m = fmaxf(m, p[d]);
        hr[idx] = m;
    }
    __syncthreads();
    for (int idx = t; idx < 64 * 64; idx += 256) {
        int r = idx >> 6, c = idx & 63;
        const float* p = hr + r * 64 + c;
        float m = p[0];
        #pragma unroll
        for (int d = 1; d < 32; d++) m = fmaxf(m, p[d * 64]);
        float v = ls[(r + 16) * 96 + (c + 16)];
        int gi = i0 + r, gj = j0 + c;
        if (gi >= 1 && gj >= 1 && v > 2.0f && v == m) {
            unsigned int k = atomicAdd(cnt, 1u);
            if (k < 2048)
                cand[k] = ((unsigned long long)__float_as_uint(v) << 32)
                        | (unsigned int)(~(unsigned int)(gi * 1024 + gj));
        }
    }
}

// sort candidates (value desc, index asc) and emit outputs; empty fast path
__global__ __launch_bounds__(1024) void k_final(
    const float* __restrict__ image, const unsigned int* __restrict__ cnt,
    const unsigned long long* __restrict__ cand, float* __restrict__ out) {
    __shared__ unsigned long long keys[2048];
    int t = threadIdx.x;
    int n = (int)cnt[0]; if (n > 2048) n = 2048;
    if (n == 0) return;                         // d_out already zeroed by k_pex
    for (int k = t; k < 2048; k += 1024) keys[k] = (k < n) ? cand[k] : 0ull;
    __syncthreads();
    for (int size = 2; size <= 2048; size <<= 1) {
        for (int stride = size >> 1; stride > 0; stride >>= 1) {
            for (int i = t; i < 2048; i += 1024) {
                int ixj = i ^ stride;
                if (ixj > i) {
                    unsigned long long a = keys[i], b = keys[ixj];
                    bool sw = ((i & size) == 0) ? (a < b) : (a > b);  // descending
                    if (sw) { keys[i] = b; keys[ixj] = a; }
                }
            }
            __syncthreads();
        }
    }
    float* roipos = out;
    float* intensity = out + 2048;
    float* rois = out + 3072;
    float* validf = out + 3072 + 1048576;
    int nw = n < 1024 ? n : 1024;
    if (t < nw) {
        unsigned long long key = keys[t];
        float val = __uint_as_float((unsigned int)(key >> 32));
        unsigned int p = ~(unsigned int)key;
        int y = (int)(p >> 10), x = (int)(p & 1023);
        int roy = y - 16, rox = x - 16;
        bool valid = (roy >= 0 && roy < 992 && rox >= 0 && rox < 992);
        int royc = roy < 0 ? 0 : (roy > 992 ? 992 : roy);
        int roxc = rox < 0 ? 0 : (rox > 992 ? 992 : rox);
        roipos[2 * t]     = valid ? (float)royc : 0.f;
        roipos[2 * t + 1] = valid ? (float)roxc : 0.f;
        intensity[t]      = valid ? val : 0.f;
        validf[t]         = valid ? 1.f : 0.f;
    }
    __syncthreads();
    for (int k = 0; k < nw; k++) {
        unsigned long long key = keys[k];
        unsigned int p = ~(unsigned int)key;
        int y = (int)(p >> 10), x = (int)(p & 1023);
        int roy = y - 16, rox = x - 16;
        if (!(roy >= 0 && roy < 992 && rox >= 0 && rox < 992)) continue;
        int u = t >> 5, vv = t & 31;
        rois[k * 1024 + t] = image[(roy + u) * 1024 + (rox + vv)];
    }
}

extern "C" void kernel_launch(void* const* d_in, const int* in_sizes, int n_in,
                              void* d_out, int out_size, void* d_ws, size_t ws_size,
                              hipStream_t stream) {
    const float* image = (const float*)d_in[0];
    const float* psf   = (const float*)d_in[1];
    float* out = (float*)d_out;
    char* ws = (char*)d_ws;
    unsigned char* img8  = (unsigned char*)(ws + WS_IMG8);
    unsigned char* bfrag = (unsigned char*)(ws + WS_BFRAG);
    float* pex = (float*)(ws + WS_PEX);
    float* result = (float*)(ws + WS_RESULT);
    unsigned int* cnt = (unsigned int*)(ws + WS_CAND);
    unsigned long long* cand = (unsigned long long*)(ws + WS_CAND + 16);

    int n4 = out_size / 4;
    hipLaunchKernelGGL(k_pex,     dim3(2144), dim3(256), 0, stream,
                       image, pex, (uint32_t*)img8, psf, bfrag, cnt, (float4*)d_out, n4);
    hipLaunchKernelGGL(k_conv,    dim3(512),  dim3(512), 0, stream,
                       (const unsigned long long*)img8, bfrag, pex, result);
    hipLaunchKernelGGL(k_maxcand, dim3(256),  dim3(256), 0, stream, result, cnt, cand);
    hipLaunchKernelGGL(k_final,   dim3(1),    dim3(1024), 0, stream, image, cnt, cand, out);
}